// Round 1
// baseline (635.471 us; speedup 1.0000x reference)
//
#include <hip/hip_runtime.h>
#include <math.h>

#define ENTITY_COUNT 1000000
#define RELATION_COUNT 1000
#define EMB_DIM 128
#define DISC_HIDDEN 512
#define MARGIN 24.0f
#define BATCH 4096
#define NEG 64

__device__ __forceinline__ float logsig(float x) {
    // stable log(sigmoid(x)) = min(x,0) - log1p(exp(-|x|))
    return fminf(x, 0.0f) - log1pf(expf(-fabsf(x)));
}

// ---------------------------------------------------------------------------
// Kernel A: per-b negative term.
// 1 block (256 thr = 4 waves) per b. Each wave handles 16 negs, two at a time
// (half-wave of 32 lanes x float4 covers one 128-float row).
// ---------------------------------------------------------------------------
__global__ __launch_bounds__(256) void neg_kernel(
    const int*   __restrict__ neg_triples,   // (B, NEG, 3)
    const float* __restrict__ ent,           // (1e6, 128)
    const float* __restrict__ rel,           // (1000, 128)
    float*       __restrict__ neg_term,      // (B) workspace
    float*       __restrict__ d_out)
{
    const int b    = blockIdx.x;
    const int tid  = threadIdx.x;
    const int wave = tid >> 6;
    const int lane = tid & 63;
    const int half = lane >> 5;   // which neg of the pair
    const int sl   = lane & 31;   // sub-lane within 32-group

    __shared__ float wsum[4];

    if (b == 0 && tid == 0) d_out[0] = 0.0f;  // harness poisons d_out; B adds after A completes

    float acc = 0.0f;
    #pragma unroll
    for (int i = 0; i < 8; ++i) {
        const int n = wave * 16 + 2 * i + half;
        const long base = ((long)b * NEG + n) * 3;
        const int ih = neg_triples[base + 0];
        const int ir = neg_triples[base + 1];
        const int it = neg_triples[base + 2];
        const float4 h4 = *(const float4*)(ent + (size_t)ih * EMB_DIM + sl * 4);
        const float4 r4 = *(const float4*)(rel + (size_t)ir * EMB_DIM + sl * 4);
        const float4 t4 = *(const float4*)(ent + (size_t)it * EMB_DIM + sl * 4);
        float s = fabsf(h4.x + r4.x - t4.x)
                + fabsf(h4.y + r4.y - t4.y)
                + fabsf(h4.z + r4.z - t4.z)
                + fabsf(h4.w + r4.w - t4.w);
        // reduce across the 32-lane group (all lanes end with the row sum)
        s += __shfl_xor(s, 16);
        s += __shfl_xor(s, 8);
        s += __shfl_xor(s, 4);
        s += __shfl_xor(s, 2);
        s += __shfl_xor(s, 1);
        acc += logsig(MARGIN - s);
    }
    // combine the two 32-groups of this wave (each counted 8 negs)
    acc += __shfl_xor(acc, 32);
    if (lane == 0) wsum[wave] = acc;
    __syncthreads();
    if (tid == 0) {
        const float t = wsum[0] + wsum[1] + wsum[2] + wsum[3];
        neg_term[b] = t * (1.0f / NEG);
    }
}

// ---------------------------------------------------------------------------
// Kernel B: positive side + discriminator MLP + final weighted sum.
// 16 b's per block of 512 threads. diff staged in LDS; thread j owns hidden
// unit j (DISC_HIDDEN == blockDim) and accumulates all 16 b's per W1 column
// element (W1 row-major -> coalesced loads across threads).
// ---------------------------------------------------------------------------
#define TB 16
__global__ __launch_bounds__(512) void pos_kernel(
    const int*   __restrict__ pos_triples,   // (B, 3)
    const float* __restrict__ ent,
    const float* __restrict__ rel,
    const float* __restrict__ W1,            // (128, 512)
    const float* __restrict__ b1,            // (512)
    const float* __restrict__ W2,            // (512)
    const float* __restrict__ b2,            // (1)
    const float* __restrict__ neg_term,      // (B)
    float*       __restrict__ d_out)
{
    const int b0  = blockIdx.x * TB;
    const int tid = threadIdx.x;

    __shared__ float diff[TB][EMB_DIM];  // 8 KB
    __shared__ float dpos[TB];
    __shared__ float zred[8][TB];

    // ---- phase 1: gather h,r,t; diff = h+r-t; d_pos = sum|diff| ----
    {
        const int bl = tid >> 5;          // 0..15 local b
        const int sl = tid & 31;          // float4 slot
        const long base = (long)(b0 + bl) * 3;
        const int ih = pos_triples[base + 0];
        const int ir = pos_triples[base + 1];
        const int it = pos_triples[base + 2];
        const float4 h4 = *(const float4*)(ent + (size_t)ih * EMB_DIM + sl * 4);
        const float4 r4 = *(const float4*)(rel + (size_t)ir * EMB_DIM + sl * 4);
        const float4 t4 = *(const float4*)(ent + (size_t)it * EMB_DIM + sl * 4);
        float4 d4;
        d4.x = h4.x + r4.x - t4.x;
        d4.y = h4.y + r4.y - t4.y;
        d4.z = h4.z + r4.z - t4.z;
        d4.w = h4.w + r4.w - t4.w;
        *(float4*)(&diff[bl][sl * 4]) = d4;
        float s = fabsf(d4.x) + fabsf(d4.y) + fabsf(d4.z) + fabsf(d4.w);
        s += __shfl_xor(s, 16);
        s += __shfl_xor(s, 8);
        s += __shfl_xor(s, 4);
        s += __shfl_xor(s, 2);
        s += __shfl_xor(s, 1);
        if (sl == 0) dpos[bl] = s;
    }
    __syncthreads();

    // ---- phase 2: hidden layer, thread j = hidden unit ----
    const int j = tid;
    float acc[TB];
    const float bias1 = b1[j];
    #pragma unroll
    for (int q = 0; q < TB; ++q) acc[q] = bias1;

    #pragma unroll 4
    for (int k = 0; k < EMB_DIM; ++k) {
        const float w = W1[(size_t)k * DISC_HIDDEN + j];
        #pragma unroll
        for (int q = 0; q < TB; ++q) acc[q] = fmaf(diff[q][k], w, acc[q]);
    }

    const float w2 = W2[j];
    float zp[TB];
    #pragma unroll
    for (int q = 0; q < TB; ++q) zp[q] = fmaxf(acc[q], 0.0f) * w2;

    // reduce each zp over the 64-lane wave
    #pragma unroll
    for (int q = 0; q < TB; ++q) {
        float v = zp[q];
        v += __shfl_xor(v, 32);
        v += __shfl_xor(v, 16);
        v += __shfl_xor(v, 8);
        v += __shfl_xor(v, 4);
        v += __shfl_xor(v, 2);
        v += __shfl_xor(v, 1);
        zp[q] = v;
    }
    const int wv = tid >> 6;
    if ((tid & 63) == 0) {
        #pragma unroll
        for (int q = 0; q < TB; ++q) zred[wv][q] = zp[q];
    }
    __syncthreads();

    // ---- phase 3: conf, loss, global accumulate ----
    if (tid < TB) {
        float z = b2[0];
        #pragma unroll
        for (int w = 0; w < 8; ++w) z += zred[w][tid];
        const float conf = 1.0f / (1.0f + expf(-z));
        const float pt   = -logsig(MARGIN - dpos[tid]);
        const float loss = conf * (pt + neg_term[b0 + tid]);
        atomicAdd(d_out, loss);
    }
}

extern "C" void kernel_launch(void* const* d_in, const int* in_sizes, int n_in,
                              void* d_out, int out_size, void* d_ws, size_t ws_size,
                              hipStream_t stream) {
    const int*   pos_triples = (const int*)  d_in[0];
    const int*   neg_triples = (const int*)  d_in[1];
    // d_in[2] = negative_sample_size (== NEG, compile-time)
    const float* ent         = (const float*)d_in[3];
    const float* rel         = (const float*)d_in[4];
    const float* W1          = (const float*)d_in[5];
    const float* b1          = (const float*)d_in[6];
    const float* W2          = (const float*)d_in[7];
    const float* b2          = (const float*)d_in[8];
    float* out      = (float*)d_out;
    float* neg_term = (float*)d_ws;   // B floats

    neg_kernel<<<BATCH, 256, 0, stream>>>(neg_triples, ent, rel, neg_term, out);
    pos_kernel<<<BATCH / TB, 512, 0, stream>>>(pos_triples, ent, rel, W1, b1, W2, b2,
                                               neg_term, out);
}